// Round 1
// baseline (235.678 us; speedup 1.0000x reference)
//
#include <hip/hip_runtime.h>
#include <math.h>

#define PP   7
#define NDIR 49
#define CIN  3
#define KK   147      // CIN * 49
#define KPAD 160      // bf16 B row stride: 5 k-steps of 32, zero-padded tail
#define EE   384
#define HH   224
#define WW   224
#define GG   16       // patches per block
#define TB   256
#define SSTR 17       // samp LDS row stride (+1 pad: conflict-free A reads)
#define NPX  112      // GG*PP pixel columns per block strip

typedef __attribute__((ext_vector_type(8))) __bf16 bf16x8;
typedef __attribute__((ext_vector_type(4))) float  f32x4;

__device__ __forceinline__ float sigmoidf_(float v) {
    return 1.0f / (1.0f + expf(-v));
}

// ---- K0: pack proj_w (E,K) fp32 -> bf16 [E][KPAD], zero-padded (RNE like (__bf16) cast)
__global__ void pack_pw_kernel(const float* __restrict__ pw, unsigned short* __restrict__ pwB) {
    int idx = blockIdx.x * blockDim.x + threadIdx.x;
    if (idx < EE * KPAD) {
        int e = idx / KPAD;
        int k = idx - e * KPAD;
        float v = (k < KK) ? pw[e * KK + k] : 0.0f;
        __bf16 h = (__bf16)v;
        pwB[idx] = *(unsigned short*)&h;
    }
}

// ---- K0b: repack x NCHW fp32 -> NHW4 fp32 (channel-interleaved, 4th lane zero).
// Turns every bilinear corner gather (3 scattered dword loads, planes 200KB apart)
// into ONE aligned global_load_dwordx4.
__global__ void pack_x_kernel(const float* __restrict__ x, float* __restrict__ xp, int npix) {
    int idx = blockIdx.x * blockDim.x + threadIdx.x;
    if (idx >= npix) return;
    int b = idx / (HH * WW);
    int p = idx - b * (HH * WW);
    const float* xb = x + (size_t)b * (CIN * HH * WW) + p;
    f32x4 v;
    v[0] = xb[0];
    v[1] = xb[HH * WW];
    v[2] = xb[2 * HH * WW];
    v[3] = 0.0f;
    *(f32x4*)(xp + (size_t)idx * 4) = v;
}

// ---- K1: fused metric-conv + derived params + gather + MFMA projection GEMM.
// One block = 16 patches (one 7x112 pixel strip). The metric conv is patch-local
// (stride-P VALID), so params are computed in-block: no params_kernel, no der
// global round-trip, no extra kernel gap.
template<bool PACKED>
__launch_bounds__(TB)
__global__ void fused_kernel(const float* __restrict__ x,    // planar NCHW (fallback path)
                             const float* __restrict__ xp,   // packed NHW4 (main path)
                             const float* __restrict__ mw,
                             const float* __restrict__ mb,
                             const unsigned short* __restrict__ pwB,
                             const float* __restrict__ pb,
                             float* __restrict__ out) {
    __shared__ float mws[7 * KK];        // 4116 B
    __shared__ float dirs[NDIR][3];      //  588 B
    __shared__ float par_s[GG][8];       //  512 B
    __shared__ float der_s[GG][5];       //  320 B
    // union buffer: phase A = staged pixel strip (PACKED: [7][112][4] = 3136 fl;
    // planar: [3][7][112] = 2352 fl); phase B = samp[147][17] = 2499 fl.
    __shared__ float buf[3136];          // 12544 B;  total LDS ~= 18 KB -> 8 blocks/CU

    const int t   = threadIdx.x;
    const int blk = blockIdx.x;
    const int b   = blk >> 6;
    const int rem = blk & 63;
    const int hp  = rem >> 1;
    const int wp0 = (rem & 1) * GG;
    const size_t m0 = (size_t)blk * GG;
    const int row0 = hp * PP;
    const int col0 = wp0 * PP;

    // ---- init: metric weights + direction table
    for (int i = t; i < 7 * KK; i += TB) mws[i] = mw[i];
    if (t >= 64 && t < 64 + NDIR) {
        int n = t - 64;
        float u0, u1, s;
        if (n == 0)      { u0 = 1.0f; u1 = 0.0f; s = 0.0f; }
        else if (n < 9)  { float th = (float)(n - 1)  * 0.78539816339744831f; u0 = cosf(th); u1 = sinf(th); s = 0.33333334f; }
        else if (n < 25) { float th = (float)(n - 9)  * 0.39269908169872414f; u0 = cosf(th); u1 = sinf(th); s = 0.66666669f; }
        else             { float th = (float)(n - 25) * 0.26179938779914941f; u0 = cosf(th); u1 = sinf(th); s = 1.0f; }
        dirs[n][0] = u0; dirs[n][1] = u1; dirs[n][2] = s;
    }

    // ---- stage the block's 7x112 pixel strip into LDS (coalesced)
    if (PACKED) {
        for (int item = t; item < 7 * NPX; item += TB) {
            int i = item / NPX, px = item - i * NPX;
            f32x4 v = *(const f32x4*)(xp + ((size_t)((b * HH + row0 + i) * WW) + col0 + px) * 4);
            *(f32x4*)&buf[item * 4] = v;   // xs[i][px][c]
        }
    } else {
        for (int item = t; item < CIN * 7 * NPX; item += TB) {
            int c = item / (7 * NPX), r2 = item - c * (7 * NPX);
            int i = r2 / NPX, px = r2 - i * NPX;
            buf[item] = x[(size_t)b * (CIN * HH * WW) + (size_t)c * (HH * WW)
                          + (size_t)(row0 + i) * WW + col0 + px];   // xs[c][i][px]
        }
    }
    __syncthreads();

    // ---- metric conv: 7 params x 16 patches = 112 dot products of length 147
    if (t < 112) {
        int prm = t >> 4, g = t & 15;
        float acc = mb[prm];
        const float* wrow = &mws[prm * KK];
        #pragma unroll
        for (int c = 0; c < CIN; ++c) {
            #pragma unroll
            for (int i = 0; i < 7; ++i) {
                #pragma unroll
                for (int j = 0; j < 7; ++j) {
                    float xv = PACKED ? buf[(i * NPX + g * 7 + j) * 4 + c]
                                      : buf[(c * 7 + i) * NPX + g * 7 + j];
                    acc = fmaf(xv, wrow[c * 49 + i * 7 + j], acc);
                }
            }
        }
        par_s[g][prm] = acc;
    }
    __syncthreads();

    // ---- derived quantities (proven math from params_kernel)
    if (t < GG) {
        float a0 = par_s[t][0], a1 = par_s[t][1], a2 = par_s[t][2], a3 = par_s[t][3];
        float a4 = par_s[t][4], a5 = par_s[t][5], a6 = par_s[t][6];
        float nrm = sqrtf(a0 * a0 + a1 * a1);
        float inv = 1.0f / fmaxf(nrm, 1e-12f);
        float v0 = a0 * inv, v1 = a1 * inv;
        float e0 = 2.0f * sigmoidf_(a2);
        float e1 = 2.0f * sigmoidf_(a3);
        float sc = 0.5f + 1.5f * sigmoidf_(a4);
        e0 *= sc; e1 *= sc;
        float wn  = sqrtf(a5 * a5 + a6 * a6);
        float wsc = 0.5f * sigmoidf_(wn);
        der_s[t][0] = e0 * v0 * v0 + e1 * v1 * v1;
        der_s[t][1] = (e0 - e1) * v0 * v1;
        der_s[t][2] = e0 * v1 * v1 + e1 * v0 * v0;
        der_s[t][3] = a5 * wsc;
        der_s[t][4] = a6 * wsc;
    }
    __syncthreads();

    // ---- positions + bilinear gather into samp (buf reused: xs is dead past here)
    const float* xb = x + (size_t)b * (CIN * HH * WW);
    const size_t pbase = (size_t)b * (HH * WW);
    for (int item = t; item < GG * NDIR; item += TB) {
        int g = item / NDIR;
        int n = item - g * NDIR;
        float u0 = dirs[n][0], u1 = dirs[n][1], s = dirs[n][2];
        float M00 = der_s[g][0], M01 = der_s[g][1], M11 = der_s[g][2];
        float w0 = der_s[g][3], w1 = der_s[g][4];
        float quad  = u0 * u0 * M00 + 2.0f * u0 * u1 * M01 + u1 * u1 * M11;
        float drift = w0 * u0 + w1 * u1;
        float F = sqrtf(quad + 1e-6f) + drift;
        float r = s / (F + 1e-6f);
        float py = (float)(row0 + 3) + u1 * r;
        float px = (float)(col0 + g * PP + 3) + u0 * r;
        float y0f = floorf(py), x0f = floorf(px);
        float y1f = y0f + 1.0f, x1f = x0f + 1.0f;
        float wy = py - y0f, wx = px - x0f;
        bool vy0 = (y0f >= 0.0f) && (y0f <= (float)(HH - 1));
        bool vy1 = (y1f >= 0.0f) && (y1f <= (float)(HH - 1));
        bool vx0 = (x0f >= 0.0f) && (x0f <= (float)(WW - 1));
        bool vx1 = (x1f >= 0.0f) && (x1f <= (float)(WW - 1));
        int iy0 = (int)fminf(fmaxf(y0f, 0.0f), (float)(HH - 1));
        int iy1 = (int)fminf(fmaxf(y1f, 0.0f), (float)(HH - 1));
        int ix0 = (int)fminf(fmaxf(x0f, 0.0f), (float)(WW - 1));
        int ix1 = (int)fminf(fmaxf(x1f, 0.0f), (float)(WW - 1));
        float w00 = (1.0f - wy) * (1.0f - wx);
        float w01 = (1.0f - wy) * wx;
        float w10 = wy * (1.0f - wx);
        float w11 = wy * wx;
        if (PACKED) {
            float c00 = w00 * ((vy0 && vx0) ? 1.0f : 0.0f);
            float c01 = w01 * ((vy0 && vx1) ? 1.0f : 0.0f);
            float c10 = w10 * ((vy1 && vx0) ? 1.0f : 0.0f);
            float c11 = w11 * ((vy1 && vx1) ? 1.0f : 0.0f);
            f32x4 q00 = *(const f32x4*)(xp + (pbase + (size_t)(iy0 * WW + ix0)) * 4);
            f32x4 q01 = *(const f32x4*)(xp + (pbase + (size_t)(iy0 * WW + ix1)) * 4);
            f32x4 q10 = *(const f32x4*)(xp + (pbase + (size_t)(iy1 * WW + ix0)) * 4);
            f32x4 q11 = *(const f32x4*)(xp + (pbase + (size_t)(iy1 * WW + ix1)) * 4);
            #pragma unroll
            for (int c = 0; c < CIN; ++c) {
                buf[(c * NDIR + n) * SSTR + g] =
                    q00[c] * c00 + q01[c] * c01 + q10[c] * c10 + q11[c] * c11;
            }
        } else {
            #pragma unroll
            for (int c = 0; c < CIN; ++c) {
                const float* xc = xb + c * (HH * WW);
                float v00 = (vy0 && vx0) ? xc[iy0 * WW + ix0] : 0.0f;
                float v01 = (vy0 && vx1) ? xc[iy0 * WW + ix1] : 0.0f;
                float v10 = (vy1 && vx0) ? xc[iy1 * WW + ix0] : 0.0f;
                float v11 = (vy1 && vx1) ? xc[iy1 * WW + ix1] : 0.0f;
                buf[(c * NDIR + n) * SSTR + g] =
                    v00 * w00 + v01 * w01 + v10 * w10 + v11 * w11;
            }
        }
    }
    __syncthreads();

    // ---- MFMA projection GEMM; A: fp32 LDS + in-register cvt,
    //      B: bf16x8 vector loads from packed pwB (16 B/lane)
    const int lane = t & 63;
    const int wv   = t >> 6;           // 0..3; wave handles 6 N-tiles
    const int nrow = lane & 15;
    const int hi   = lane >> 4;

    bf16x8 afr[5];
    #pragma unroll
    for (int ks = 0; ks < 5; ++ks) {
        #pragma unroll
        for (int j = 0; j < 8; ++j) {
            int k = ks * 32 + hi * 8 + j;
            float v = (k < KK) ? buf[k * SSTR + nrow] : 0.0f;
            afr[ks][j] = (__bf16)v;
        }
    }

    #pragma unroll
    for (int q = 0; q < 6; ++q) {
        int tile = wv * 6 + q;
        int e    = tile * 16 + nrow;
        const unsigned short* brow = pwB + (size_t)e * KPAD + hi * 8;
        f32x4 acc = {0.0f, 0.0f, 0.0f, 0.0f};
        #pragma unroll
        for (int ks = 0; ks < 5; ++ks) {
            bf16x8 bfr = *(const bf16x8*)&brow[ks * 32];
            acc = __builtin_amdgcn_mfma_f32_16x16x32_bf16(afr[ks], bfr, acc, 0, 0, 0);
        }
        float bias = pb[e];
        #pragma unroll
        for (int r = 0; r < 4; ++r) {
            out[(m0 + hi * 4 + r) * EE + e] = acc[r] + bias;
        }
    }
}

extern "C" void kernel_launch(void* const* d_in, const int* in_sizes, int n_in,
                              void* d_out, int out_size, void* d_ws, size_t ws_size,
                              hipStream_t stream) {
    const float* x  = (const float*)d_in[0];
    const float* mw = (const float*)d_in[1];
    const float* mb = (const float*)d_in[2];
    const float* pw = (const float*)d_in[3];
    const float* pb = (const float*)d_in[4];
    float* out = (float*)d_out;

    unsigned short* pwB = (unsigned short*)d_ws;                       // 120 KB
    float* xp = (float*)((char*)d_ws + (size_t)(1 << 17));             // packed NHW4 image

    const int B = in_sizes[0] / (CIN * HH * WW);   // 64
    const int npix = B * HH * WW;
    const size_t need = (size_t)(1 << 17) + (size_t)npix * 4 * sizeof(float);
    const bool packed = ws_size >= need;

    pack_pw_kernel<<<(EE * KPAD + 255) / 256, 256, 0, stream>>>(pw, pwB);
    if (packed) {
        pack_x_kernel<<<(npix + 255) / 256, 256, 0, stream>>>(x, xp, npix);
        fused_kernel<true><<<B * 64, TB, 0, stream>>>(x, xp, mw, mb, pwB, pb, out);
    } else {
        fused_kernel<false><<<B * 64, TB, 0, stream>>>(x, xp, mw, mb, pwB, pb, out);
    }
}

// Round 2
// 200.100 us; speedup vs baseline: 1.1778x; 1.1778x over previous
//
#include <hip/hip_runtime.h>
#include <math.h>

#define PP   7
#define NDIR 49
#define CIN  3
#define KK   147      // CIN * 49
#define KPAD 160      // bf16 B row stride: 5 k-steps of 32, zero-padded tail
#define EE   384
#define HH   224
#define WW   224
#define GG   16       // patches per block
#define TB   256
#define SSTR 17       // samp LDS row stride (+1 pad: conflict-free A reads)
#define NPX  112      // GG*PP pixel columns per block strip

typedef __attribute__((ext_vector_type(8))) __bf16 bf16x8;
typedef __attribute__((ext_vector_type(4))) float  f32x4;

__device__ __forceinline__ float sigmoidf_(float v) {
    return 1.0f / (1.0f + expf(-v));
}

// ---- K0: fused pack. (a) proj_w (E,K) fp32 -> bf16 [E][KPAD]; (b) x NCHW -> NHW4
// fp32 (channel-interleaved float4, 4th lane zero). 4 pixels/thread, all loads and
// stores dwordx4.
__global__ void pack_kernel(const float* __restrict__ x,
                            const float* __restrict__ pw,
                            float* __restrict__ xp,
                            unsigned short* __restrict__ pwB,
                            int npix4) {
    int idx = blockIdx.x * blockDim.x + threadIdx.x;
    if (idx < EE * KPAD) {
        int e = idx / KPAD;
        int k = idx - e * KPAD;
        float v = (k < KK) ? pw[e * KK + k] : 0.0f;
        __bf16 h = (__bf16)v;
        pwB[idx] = *(unsigned short*)&h;
    }
    if (idx < npix4) {
        const int ppi = HH * WW / 4;         // 12544 pixel-quads per image
        int b = idx / ppi;
        int p = (idx - b * ppi) * 4;
        const float* xb = x + (size_t)b * (CIN * HH * WW) + p;
        f32x4 r0 = *(const f32x4*)(xb);
        f32x4 r1 = *(const f32x4*)(xb + HH * WW);
        f32x4 r2 = *(const f32x4*)(xb + 2 * HH * WW);
        float* op = xp + ((size_t)b * (HH * WW) + p) * 4;
        #pragma unroll
        for (int i = 0; i < 4; ++i) {
            f32x4 v = {r0[i], r1[i], r2[i], 0.0f};
            *(f32x4*)(op + i * 4) = v;
        }
    }
}

// ---- K1: fused metric-conv + derived params + gather + MFMA projection GEMM.
// One block = 16 patches (one 7x112 pixel strip). __launch_bounds__(256,8):
// 8 waves/EU -> 8 blocks/CU -> VGPR capped at 64 (round-1 lesson: without this
// the compiler allocates 100 VGPRs and occupancy collapses to ~2 blocks/CU,
// un-hiding the scattered-gather latency).
template<bool PACKED>
__launch_bounds__(TB, 8)
__global__ void fused_kernel(const float* __restrict__ x,    // planar NCHW (fallback path)
                             const float* __restrict__ xp,   // packed NHW4 (main path)
                             const float* __restrict__ mw,
                             const float* __restrict__ mb,
                             const unsigned short* __restrict__ pwB,
                             const float* __restrict__ pb,
                             float* __restrict__ out) {
    __shared__ float mws[7 * KK];        // 4116 B
    __shared__ float dirs[NDIR][3];      //  588 B
    __shared__ float par_s[GG][8];       //  512 B
    __shared__ float der_s[GG][5];       //  320 B
    // union buffer: phase A = staged pixel strip (PACKED: [7][112][4] = 3136 fl;
    // planar: [3][7][112] = 2352 fl); phase B = samp[147][17] = 2499 fl.
    __shared__ __align__(16) float buf[3136];   // 12544 B; total LDS ~18 KB -> 8 blocks/CU

    const int t   = threadIdx.x;
    const int blk = blockIdx.x;
    const int b   = blk >> 6;
    const int rem = blk & 63;
    const int hp  = rem >> 1;
    const int wp0 = (rem & 1) * GG;
    const size_t m0 = (size_t)blk * GG;
    const int row0 = hp * PP;
    const int col0 = wp0 * PP;

    // ---- init: metric weights + direction table
    for (int i = t; i < 7 * KK; i += TB) mws[i] = mw[i];
    if (t >= 64 && t < 64 + NDIR) {
        int n = t - 64;
        float u0, u1, s;
        if (n == 0)      { u0 = 1.0f; u1 = 0.0f; s = 0.0f; }
        else if (n < 9)  { float th = (float)(n - 1)  * 0.78539816339744831f; u0 = cosf(th); u1 = sinf(th); s = 0.33333334f; }
        else if (n < 25) { float th = (float)(n - 9)  * 0.39269908169872414f; u0 = cosf(th); u1 = sinf(th); s = 0.66666669f; }
        else             { float th = (float)(n - 25) * 0.26179938779914941f; u0 = cosf(th); u1 = sinf(th); s = 1.0f; }
        dirs[n][0] = u0; dirs[n][1] = u1; dirs[n][2] = s;
    }

    // ---- stage the block's 7x112 pixel strip into LDS (coalesced)
    if (PACKED) {
        for (int item = t; item < 7 * NPX; item += TB) {
            int i = item / NPX, px = item - i * NPX;
            f32x4 v = *(const f32x4*)(xp + ((size_t)((b * HH + row0 + i) * WW) + col0 + px) * 4);
            *(f32x4*)&buf[item * 4] = v;   // xs[i][px][c]
        }
    } else {
        for (int item = t; item < CIN * 7 * NPX; item += TB) {
            int c = item / (7 * NPX), r2 = item - c * (7 * NPX);
            int i = r2 / NPX, px = r2 - i * NPX;
            buf[item] = x[(size_t)b * (CIN * HH * WW) + (size_t)c * (HH * WW)
                          + (size_t)(row0 + i) * WW + col0 + px];   // xs[c][i][px]
        }
    }
    __syncthreads();

    // ---- metric conv: 7 params x 16 patches = 112 dot products of length 147.
    // Deliberately NOT unrolled across c/i: keeps the register-pressure peak low
    // so the (256,8) launch bound is met without spills. ~21 short iterations on
    // 112 threads; off the critical path.
    if (t < 112) {
        int prm = t >> 4, g = t & 15;
        float acc = mb[prm];
        const float* wrow = &mws[prm * KK];
        if (PACKED) {
            #pragma unroll 1
            for (int c = 0; c < CIN; ++c) {
                #pragma unroll 1
                for (int i = 0; i < 7; ++i) {
                    const float* bp = &buf[(i * NPX + g * 7) * 4 + c];
                    const float* wr = &wrow[c * 49 + i * 7];
                    #pragma unroll
                    for (int j = 0; j < 7; ++j)
                        acc = fmaf(bp[j * 4], wr[j], acc);
                }
            }
        } else {
            #pragma unroll 1
            for (int c = 0; c < CIN; ++c) {
                #pragma unroll 1
                for (int i = 0; i < 7; ++i) {
                    const float* bp = &buf[(c * 7 + i) * NPX + g * 7];
                    const float* wr = &wrow[c * 49 + i * 7];
                    #pragma unroll
                    for (int j = 0; j < 7; ++j)
                        acc = fmaf(bp[j], wr[j], acc);
                }
            }
        }
        par_s[g][prm] = acc;
    }
    __syncthreads();

    // ---- derived quantities (proven math)
    if (t < GG) {
        float a0 = par_s[t][0], a1 = par_s[t][1], a2 = par_s[t][2], a3 = par_s[t][3];
        float a4 = par_s[t][4], a5 = par_s[t][5], a6 = par_s[t][6];
        float nrm = sqrtf(a0 * a0 + a1 * a1);
        float inv = 1.0f / fmaxf(nrm, 1e-12f);
        float v0 = a0 * inv, v1 = a1 * inv;
        float e0 = 2.0f * sigmoidf_(a2);
        float e1 = 2.0f * sigmoidf_(a3);
        float sc = 0.5f + 1.5f * sigmoidf_(a4);
        e0 *= sc; e1 *= sc;
        float wn  = sqrtf(a5 * a5 + a6 * a6);
        float wsc = 0.5f * sigmoidf_(wn);
        der_s[t][0] = e0 * v0 * v0 + e1 * v1 * v1;
        der_s[t][1] = (e0 - e1) * v0 * v1;
        der_s[t][2] = e0 * v1 * v1 + e1 * v0 * v0;
        der_s[t][3] = a5 * wsc;
        der_s[t][4] = a6 * wsc;
    }
    __syncthreads();

    // ---- positions + bilinear gather into samp (buf reused: xs is dead past here)
    const float* xb = x + (size_t)b * (CIN * HH * WW);
    const size_t pbase = (size_t)b * (HH * WW);
    for (int item = t; item < GG * NDIR; item += TB) {
        int g = item / NDIR;
        int n = item - g * NDIR;
        float u0 = dirs[n][0], u1 = dirs[n][1], s = dirs[n][2];
        float M00 = der_s[g][0], M01 = der_s[g][1], M11 = der_s[g][2];
        float w0 = der_s[g][3], w1 = der_s[g][4];
        float quad  = u0 * u0 * M00 + 2.0f * u0 * u1 * M01 + u1 * u1 * M11;
        float drift = w0 * u0 + w1 * u1;
        float F = sqrtf(quad + 1e-6f) + drift;
        float r = s / (F + 1e-6f);
        float py = (float)(row0 + 3) + u1 * r;
        float px = (float)(col0 + g * PP + 3) + u0 * r;
        float y0f = floorf(py), x0f = floorf(px);
        float y1f = y0f + 1.0f, x1f = x0f + 1.0f;
        float wy = py - y0f, wx = px - x0f;
        bool vy0 = (y0f >= 0.0f) && (y0f <= (float)(HH - 1));
        bool vy1 = (y1f >= 0.0f) && (y1f <= (float)(HH - 1));
        bool vx0 = (x0f >= 0.0f) && (x0f <= (float)(WW - 1));
        bool vx1 = (x1f >= 0.0f) && (x1f <= (float)(WW - 1));
        int iy0 = (int)fminf(fmaxf(y0f, 0.0f), (float)(HH - 1));
        int iy1 = (int)fminf(fmaxf(y1f, 0.0f), (float)(HH - 1));
        int ix0 = (int)fminf(fmaxf(x0f, 0.0f), (float)(WW - 1));
        int ix1 = (int)fminf(fmaxf(x1f, 0.0f), (float)(WW - 1));
        float w00 = (1.0f - wy) * (1.0f - wx);
        float w01 = (1.0f - wy) * wx;
        float w10 = wy * (1.0f - wx);
        float w11 = wy * wx;
        if (PACKED) {
            float c00 = w00 * ((vy0 && vx0) ? 1.0f : 0.0f);
            float c01 = w01 * ((vy0 && vx1) ? 1.0f : 0.0f);
            float c10 = w10 * ((vy1 && vx0) ? 1.0f : 0.0f);
            float c11 = w11 * ((vy1 && vx1) ? 1.0f : 0.0f);
            f32x4 q00 = *(const f32x4*)(xp + (pbase + (size_t)(iy0 * WW + ix0)) * 4);
            f32x4 q01 = *(const f32x4*)(xp + (pbase + (size_t)(iy0 * WW + ix1)) * 4);
            f32x4 q10 = *(const f32x4*)(xp + (pbase + (size_t)(iy1 * WW + ix0)) * 4);
            f32x4 q11 = *(const f32x4*)(xp + (pbase + (size_t)(iy1 * WW + ix1)) * 4);
            #pragma unroll
            for (int c = 0; c < CIN; ++c) {
                buf[(c * NDIR + n) * SSTR + g] =
                    q00[c] * c00 + q01[c] * c01 + q10[c] * c10 + q11[c] * c11;
            }
        } else {
            #pragma unroll
            for (int c = 0; c < CIN; ++c) {
                const float* xc = xb + c * (HH * WW);
                float v00 = (vy0 && vx0) ? xc[iy0 * WW + ix0] : 0.0f;
                float v01 = (vy0 && vx1) ? xc[iy0 * WW + ix1] : 0.0f;
                float v10 = (vy1 && vx0) ? xc[iy1 * WW + ix0] : 0.0f;
                float v11 = (vy1 && vx1) ? xc[iy1 * WW + ix1] : 0.0f;
                buf[(c * NDIR + n) * SSTR + g] =
                    v00 * w00 + v01 * w01 + v10 * w10 + v11 * w11;
            }
        }
    }
    __syncthreads();

    // ---- MFMA projection GEMM; A: fp32 LDS + in-register cvt,
    //      B: bf16x8 vector loads from packed pwB (16 B/lane)
    const int lane = t & 63;
    const int wv   = t >> 6;           // 0..3; wave handles 6 N-tiles
    const int nrow = lane & 15;
    const int hi   = lane >> 4;

    bf16x8 afr[5];
    #pragma unroll
    for (int ks = 0; ks < 5; ++ks) {
        #pragma unroll
        for (int j = 0; j < 8; ++j) {
            int k = ks * 32 + hi * 8 + j;
            float v = (k < KK) ? buf[k * SSTR + nrow] : 0.0f;
            afr[ks][j] = (__bf16)v;
        }
    }

    #pragma unroll
    for (int q = 0; q < 6; ++q) {
        int tile = wv * 6 + q;
        int e    = tile * 16 + nrow;
        const unsigned short* brow = pwB + (size_t)e * KPAD + hi * 8;
        f32x4 acc = {0.0f, 0.0f, 0.0f, 0.0f};
        #pragma unroll
        for (int ks = 0; ks < 5; ++ks) {
            bf16x8 bfr = *(const bf16x8*)&brow[ks * 32];
            acc = __builtin_amdgcn_mfma_f32_16x16x32_bf16(afr[ks], bfr, acc, 0, 0, 0);
        }
        float bias = pb[e];
        #pragma unroll
        for (int r = 0; r < 4; ++r) {
            out[(m0 + hi * 4 + r) * EE + e] = acc[r] + bias;
        }
    }
}

extern "C" void kernel_launch(void* const* d_in, const int* in_sizes, int n_in,
                              void* d_out, int out_size, void* d_ws, size_t ws_size,
                              hipStream_t stream) {
    const float* x  = (const float*)d_in[0];
    const float* mw = (const float*)d_in[1];
    const float* mb = (const float*)d_in[2];
    const float* pw = (const float*)d_in[3];
    const float* pb = (const float*)d_in[4];
    float* out = (float*)d_out;

    unsigned short* pwB = (unsigned short*)d_ws;                       // 120 KB (128 KB slot)
    float* xp = (float*)((char*)d_ws + (size_t)(1 << 17));             // packed NHW4 image

    const int B = in_sizes[0] / (CIN * HH * WW);   // 64
    const int npix = B * HH * WW;
    const int npix4 = npix / 4;
    const size_t need = (size_t)(1 << 17) + (size_t)npix * 4 * sizeof(float);
    const bool packed = ws_size >= need;

    if (packed) {
        int grid = (npix4 > EE * KPAD ? npix4 : EE * KPAD);
        pack_kernel<<<(grid + 255) / 256, 256, 0, stream>>>(x, pw, xp, pwB, npix4);
        fused_kernel<true><<<B * 64, TB, 0, stream>>>(x, xp, mw, mb, pwB, pb, out);
    } else {
        pack_kernel<<<(EE * KPAD + 255) / 256, 256, 0, stream>>>(x, pw, xp, pwB, 0);
        fused_kernel<false><<<B * 64, TB, 0, stream>>>(x, xp, mw, mb, pwB, pb, out);
    }
}